// Round 7
// baseline (218.726 us; speedup 1.0000x reference)
//
#include <hip/hip_runtime.h>

typedef unsigned short u16;
typedef unsigned int   u32;
typedef __attribute__((ext_vector_type(8))) short short8;   // 8 x bf16 (4 VGPRs)
typedef __attribute__((ext_vector_type(4))) float f32x4;

#define MFMA16(a, b, c) __builtin_amdgcn_mfma_f32_16x16x32_bf16(a, b, c, 0, 0, 0)

// async global->LDS, 16B per lane, lds dest = wave-uniform base + lane*16
#define GLDS(gp, lp) __builtin_amdgcn_global_load_lds(                         \
    (const __attribute__((address_space(1))) void*)(gp),                       \
    (__attribute__((address_space(3))) void*)(lp), 16, 0, 0)

constexpr int Lv = 2048, Hv = 8, Ev = 64, HE = Hv * Ev; // HE=512
constexpr float QSCALE = 0.18033688011112042f;          // 0.125 * log2(e)

__device__ __forceinline__ float bf2f(u16 u) {
    u32 x = ((u32)u) << 16;
    return __builtin_bit_cast(float, x);
}
__device__ __forceinline__ u16 f2bf(float f) {   // RNE, finite inputs
    u32 x = __builtin_bit_cast(u32, f);
    u32 r = ((x >> 16) & 1u) + 0x7fffu;
    return (u16)((x + r) >> 16);
}
__device__ __forceinline__ u32 pkbf(float a, float b) {
#if __has_builtin(__builtin_amdgcn_cvt_pk_bf16_f32)
    typedef __attribute__((ext_vector_type(2))) __bf16 bf16x2;
    bf16x2 v = __builtin_amdgcn_cvt_pk_bf16_f32(a, b);
    return __builtin_bit_cast(u32, v);
#else
    return (u32)f2bf(a) | ((u32)f2bf(b) << 16);
#endif
}
__device__ __forceinline__ float fexp2(float x) {
#if __has_builtin(__builtin_amdgcn_exp2f)
    return __builtin_amdgcn_exp2f(x);
#else
    return exp2f(x);
#endif
}

// Runtime dtype sniff (validated rounds 2-6: fp32 inputs detected correctly).
__device__ __forceinline__ int detect_isbf16(const u32* q32, int lane) {
    u32 w0 = q32[2 * lane];
    u32 w1 = q32[2 * lane + 1];
    u16 uu[4] = { (u16)(w0 & 0xffff), (u16)(w0 >> 16),
                  (u16)(w1 & 0xffff), (u16)(w1 >> 16) };
    int p = 0, z = 0;
#pragma unroll
    for (int j = 0; j < 4; ++j) {
        u16 mgn = (u16)(uu[j] & 0x7fff);
        int ex  = mgn >> 7;
        bool zero = (mgn == 0);
        bool pl   = zero || (ex >= 115 && ex <= 132);
        p += pl ? 1 : 0;
        if ((j & 1) == 0) z += zero ? 1 : 0;
    }
    int acc = p | (z << 16);
#pragma unroll
    for (int o = 1; o < 64; o <<= 1) acc += __shfl_xor(acc, o);
    int ps = acc & 0xffff, zs = acc >> 16;
    if (zs >= 100) return 0;
    return (ps >= 240) ? 1 : 0;
}

__device__ __forceinline__ short8 cvt8(const float* p) {  // 8 fp32 -> 8 bf16
    float4 a = *(const float4*)p, b4 = *(const float4*)(p + 4);
    u32 r[4] = { pkbf(a.x, a.y), pkbf(a.z, a.w), pkbf(b4.x, b4.y), pkbf(b4.z, b4.w) };
    return *(short8*)r;
}
__device__ __forceinline__ short8 cvt8s(const float* p, float s) {
    float4 a = *(const float4*)p, b4 = *(const float4*)(p + 4);
    u32 r[4] = { pkbf(a.x * s, a.y * s), pkbf(a.z * s, a.w * s),
                 pkbf(b4.x * s, b4.y * s), pkbf(b4.z * s, b4.w * s) };
    return *(short8*)r;
}

// ---------------------------------------------------------------------------
// Pre-pass: K -> bf16 reorg [bh][l][e] (kb); V -> bf16 per-64-key tiles,
// transposed + XOR-swizzled into the EXACT LDS image the main kernel wants
// (vs), so the main loop stages V with a single identity global_load_lds.
// grid = 2048 x 256: blocks 0..1023 = V tiles (bh*32+kt), 1024..2047 = K copy.
// ---------------------------------------------------------------------------
template <int ISBF>
__device__ __forceinline__ void prep_impl(const void* kv, const void* vv,
                                          u16* kb, u16* vs, float* T)
{
    const int bid = blockIdx.x, tid = threadIdx.x;
    if (bid < 1024) {
        const int bh = bid >> 5, kt = bid & 31;
        const int b = bh >> 3, h = bh & 7;
        // load 64key x 64e tile into LDS fp32 (row stride 69 to dodge banks)
        const int ky = tid >> 2, q4 = tid & 3;
        const size_t inrow = ((size_t)(b * Lv + kt * 64 + ky) * Hv + h) * Ev;
        if (ISBF) {
            const u16* ip = (const u16*)vv + inrow + q4 * 16;
#pragma unroll
            for (int j = 0; j < 16; ++j) T[ky * 69 + q4 * 16 + j] = bf2f(ip[j]);
        } else {
            const float* ip = (const float*)vv + inrow + q4 * 16;
#pragma unroll
            for (int j = 0; j < 4; ++j)
                *(float4*)&T[ky * 69 + q4 * 16 + j * 4] = *(const float4*)(ip + j * 4);
        }
        __syncthreads();
        u16* outt = vs + ((size_t)bh * 32 + kt) * 4096;
#pragma unroll
        for (int t2 = 0; t2 < 2; ++t2) {
            int ci = tid + t2 * 256;               // 0..511 output 16B chunks
            int e = ci >> 3, slot = ci & 7;
            int kc = slot ^ ((e + (e >> 3)) & 7);  // keys kc*8..kc*8+7
            u32 rr[4];
#pragma unroll
            for (int jj = 0; jj < 4; ++jj)
                rr[jj] = pkbf(T[(kc * 8 + 2 * jj) * 69 + e],
                              T[(kc * 8 + 2 * jj + 1) * 69 + e]);
            *(uint4*)&outt[ci * 8] = *(uint4*)rr;
        }
    } else {
        // K: out[(bh*2048+l)*64+e] = in[((b*2048+l)*8+h)*64+e], 16 u16/thread
        int t_lin = (bid - 1024) * 256 + tid;      // 0..262143
        int e0 = (t_lin & 3) * 16;
        int rl = t_lin >> 2;                       // bh*2048 + l
        int l = rl & 2047, bh = rl >> 11;
        int b = bh >> 3, h = bh & 7;
        size_t in0 = ((size_t)(b * Lv + l) * Hv + h) * Ev + e0;
        u32 rr[8];
        if (ISBF) {
            const u16* ip = (const u16*)kv + in0;
            *(uint4*)rr       = *(const uint4*)ip;
            *(uint4*)(rr + 4) = *(const uint4*)(ip + 8);
        } else {
            const float* ip = (const float*)kv + in0;
#pragma unroll
            for (int j = 0; j < 8; ++j) {
                float2 f = *(const float2*)(ip + j * 2);
                rr[j] = pkbf(f.x, f.y);
            }
        }
        *(uint4*)&kb[(size_t)t_lin * 16]     = *(uint4*)rr;
        *(uint4*)&kb[(size_t)t_lin * 16 + 8] = *(uint4*)(rr + 4);
    }
}

__global__ void prep_kernel(const void* qv, const void* kv, const void* vv,
                            u16* kb, u16* vs)
{
    __shared__ float T[64 * 69];
    const int isbf = detect_isbf16((const u32*)qv, threadIdx.x & 63);
    if (isbf) prep_impl<1>(kv, vv, kb, vs, T);
    else      prep_impl<0>(kv, vv, kb, vs, T);
}

// ---------------------------------------------------------------------------
// Main: fused full attention + l=0 local blend.
// grid = 512 (16 row-blocks x 32 bh), block = 512 (8 waves, 16 rows/wave).
// PRE=1: K fragments direct from global bf16 (L1-hot 8KB tile, no LDS);
//        V staged by one global_load_lds per thread (pre-swizzled image).
// PRE=0: fallback (no workspace): K direct from original layout (+cvt if
//        fp32), V register-staged as round 5.
// ---------------------------------------------------------------------------
template <int ISBF, int PRE>
__device__ __forceinline__ void attn_impl(
    const void* __restrict__ qv, const void* __restrict__ kv,
    const void* __restrict__ vv, const void* __restrict__ alphav,
    void* __restrict__ outv, const u16* __restrict__ kb,
    const u16* __restrict__ vs, u16* Vbuf, u16* PldsAll)
{
    const int tid  = threadIdx.x;          // 0..511
    const int w    = tid >> 6;
    const int lane = tid & 63;
    const int quad = lane >> 4;
    const int m    = lane & 15;

    // XCD-aware mapping: xcd = fid&7 handles bh in {4*xcd .. 4*xcd+3}.
    const int fid = blockIdx.x;
    const int bh  = (fid & 7) * 4 + ((fid >> 3) & 3);
    const int rb  = fid >> 5;
    const int b   = bh >> 3, h = bh & 7;
    const int row0 = rb * 128;

    const size_t bhoff = (size_t)b * Lv * HE + h * Ev;
    const u16*   q16 = (const u16*)qv + bhoff;
    const float* q32 = (const float*)qv + bhoff;
    const u16*   k16o = (const u16*)kv + bhoff;
    const float* k32o = (const float*)kv + bhoff;
    const u16*   v16o = (const u16*)vv + bhoff;
    const float* v32o = (const float*)vv + bhoff;
    const u16*   kbbh = kb + (size_t)bh * (Lv * Ev);
    const u16*   vsbh = vs + (size_t)bh * (32 * 4096);

    // Q fragments (pre-scaled). B-operand of the S^T MFMA.
    short8 qf[2];
    {
        size_t ro = (size_t)(row0 + w * 16 + m) * HE + quad * 8;
        if (ISBF) {
            short8 t0 = *(const short8*)(q16 + ro);
            short8 t1 = *(const short8*)(q16 + ro + 32);
#pragma unroll
            for (int j = 0; j < 8; ++j) {
                qf[0][j] = (short)f2bf(bf2f((u16)t0[j]) * QSCALE);
                qf[1][j] = (short)f2bf(bf2f((u16)t1[j]) * QSCALE);
            }
        } else {
            qf[0] = cvt8s(q32 + ro, QSCALE);
            qf[1] = cvt8s(q32 + ro + 32, QSCALE);
        }
    }

    short8 ones8;
#pragma unroll
    for (int j = 0; j < 8; ++j) ones8[j] = (short)0x3F80;   // bf16 1.0

    f32x4 O[4];
    f32x4 Ssum = f32x4{0.f, 0.f, 0.f, 0.f};
#pragma unroll
    for (int et = 0; et < 4; ++et) O[et] = f32x4{0.f, 0.f, 0.f, 0.f};

    // fallback V staging (round-5 pattern)
    const int eq = tid & 15, pp = tid >> 4;      // pp 0..31
    const int kcv = pp >> 2, pq = pp & 3;
    uint2 vr0, vr1; float4 vfa, vfb;

    auto v_load = [&](int KT) {
        if (ISBF) {
            const u16* vp = v16o + (size_t)(KT * 64 + 2 * pp) * HE + eq * 4;
            vr0 = *(const uint2*)vp; vr1 = *(const uint2*)(vp + HE);
        } else {
            const float* vp = v32o + (size_t)(KT * 64 + 2 * pp) * HE + eq * 4;
            vfa = *(const float4*)vp; vfb = *(const float4*)(vp + HE);
        }
    };
    auto v_store = [&](u16* VB) {
        if (ISBF) {
            const u16* a0 = (const u16*)&vr0;
            const u16* a1 = (const u16*)&vr1;
#pragma unroll
            for (int j = 0; j < 4; ++j) {
                int e  = eq * 4 + j;
                int sl = kcv ^ ((e + (e >> 3)) & 7);
                u32 val = (u32)a0[j] | ((u32)a1[j] << 16);
                *(u32*)&VB[e * 64 + sl * 8 + pq * 2] = val;
            }
        } else {
            float t0[4], t1[4];
            *(float4*)t0 = vfa; *(float4*)t1 = vfb;
#pragma unroll
            for (int j = 0; j < 4; ++j) {
                int e  = eq * 4 + j;
                int sl = kcv ^ ((e + (e >> 3)) & 7);
                *(u32*)&VB[e * 64 + sl * 8 + pq * 2] = pkbf(t0[j], t1[j]);
            }
        }
    };

    // prologue: stage V tile 0 into buffer 0
    if (PRE) { GLDS(vsbh + tid * 8, Vbuf + tid * 8); }
    else     { v_load(0); v_store(Vbuf); }
    __syncthreads();

    u16* Pw = PldsAll + w * 1024;

    for (int kt = 0; kt < 32; ++kt) {
        u16* cur = Vbuf + (kt & 1) * 4096;
        u16* nxt = Vbuf + ((kt & 1) ^ 1) * 4096;

        if (!PRE && kt < 31) v_load(kt + 1);

        // ---- S^T = K (Q*c)^T, K fragments straight from global ----
        f32x4 St[4];
#pragma unroll
        for (int nt = 0; nt < 4; ++nt) St[nt] = f32x4{0.f, 0.f, 0.f, 0.f};
#pragma unroll
        for (int c = 0; c < 2; ++c) {
#pragma unroll
            for (int nt = 0; nt < 4; ++nt) {
                short8 kf;
                if (PRE) {
                    kf = *(const short8*)(kbbh +
                         ((size_t)kt * 64 + nt * 16 + m) * 64 + c * 32 + quad * 8);
                } else if (ISBF) {
                    kf = *(const short8*)(k16o +
                         (size_t)(kt * 64 + nt * 16 + m) * HE + c * 32 + quad * 8);
                } else {
                    kf = cvt8(k32o +
                         (size_t)(kt * 64 + nt * 16 + m) * HE + c * 32 + quad * 8);
                }
                St[nt] = MFMA16(kf, qf[c], St[nt]);
            }
        }

        // issue async V stage for kt+1 AFTER the K loads (vmcnt ordering)
        if (PRE && kt < 31)
            GLDS(vsbh + (size_t)(kt + 1) * 4096 + tid * 8, nxt + tid * 8);

        // ---- P = exp2(St): 4 consecutive keys/lane -> one b64 store per nt ----
#pragma unroll
        for (int nt = 0; nt < 4; ++nt) {
            u32 u0 = pkbf(fexp2(St[nt][0]), fexp2(St[nt][1]));
            u32 u1 = pkbf(fexp2(St[nt][2]), fexp2(St[nt][3]));
            int G   = 2 * nt + (quad >> 1);
            int off = m * 64 + ((G ^ (m & 7)) * 8) + (quad & 1) * 4;
            uint2 val; val.x = u0; val.y = u1;
            *(uint2*)&Pw[off] = val;   // per-wave buffer, no barrier needed
        }

        // ---- O += P V;  Ssum += P * ones ----
#pragma unroll
        for (int c = 0; c < 2; ++c) {
            int Gp = (4 * c + quad) ^ (m & 7);
            short8 pf = *(const short8*)&Pw[m * 64 + Gp * 8];
            Ssum = MFMA16(pf, ones8, Ssum);
#pragma unroll
            for (int et = 0; et < 4; ++et) {
                int e  = et * 16 + m;
                int sl = (4 * c + quad) ^ ((e + (e >> 3)) & 7);
                short8 vf = *(const short8*)&cur[e * 64 + sl * 8];
                O[et] = MFMA16(pf, vf, O[et]);
            }
        }

        if (kt < 31) {
            if (!PRE) v_store(nxt);
            __syncthreads();   // drains GLDS (PRE) / orders v_store (fallback)
        }
    }

    // ---- l=0 local attention (wave 0 of rb==0 blocks) ----
    float locv[4] = {0.f, 0.f, 0.f, 0.f};
    float wgt = 0.f;
    const bool isrow0 = (rb == 0) && (w == 0) && (quad == 0);
    if (rb == 0 && w == 0) {
        const int e = lane;
        const size_t base = bhoff + e;
#define LDIN(p, i) (ISBF ? bf2f(((const u16*)(p))[i]) : ((const float*)(p))[i])
        float qe = LDIN(qv, base);
        float s[9];
#pragma unroll
        for (int j = 0; j < 9; ++j) {
            float prod = qe * LDIN(kv, base + (size_t)j * HE);
#pragma unroll
            for (int o = 1; o < 64; o <<= 1) prod += __shfl_xor(prod, o);
            s[j] = prod * 0.125f;
        }
        float mx = s[0];
#pragma unroll
        for (int j = 1; j < 9; ++j) mx = fmaxf(mx, s[j]);
        float we[9];
#pragma unroll
        for (int j = 0; j < 9; ++j) we[j] = expf(s[j] - mx);
        float denom = 9.f * we[0];
        float acc   = 9.f * we[0] * LDIN(vv, base);
#pragma unroll
        for (int j = 1; j < 9; ++j) {
            denom += we[j];
            acc   += we[j] * LDIN(vv, base + (size_t)j * HE);
        }
        float loc = acc / denom;

        float a;
        if (ISBF) {
            a = bf2f(((const u16*)alphav)[0]);
            if (!(a >= 0.0f && a <= 1.0f)) {
                float af = ((const float*)alphav)[0];
                if (af >= 0.0f && af <= 1.0f) a = af;
            }
        } else {
            a = ((const float*)alphav)[0];
            if (!(a >= 0.0f && a <= 1.0f)) {
                float ab = bf2f(((const u16*)alphav)[0]);
                if (ab >= 0.0f && ab <= 1.0f) a = ab;
            }
        }
        wgt = 1.f / (1.f + expf(-a));
#pragma unroll
        for (int et = 0; et < 4; ++et) locv[et] = __shfl(loc, et * 16 + m);
#undef LDIN
    }

    // ---- epilogue: normalize by MFMA row-sum, blend row 0, store ----
#pragma unroll
    for (int r = 0; r < 4; ++r) {
        float inv = 1.0f / Ssum[r];
        int row = row0 + w * 16 + quad * 4 + r;
        size_t oo = (size_t)(b * Lv + row) * HE + h * Ev + m;
        bool blend = isrow0 && (r == 0);
#pragma unroll
        for (int et = 0; et < 4; ++et) {
            float res = O[et][r] * inv;
            if (blend) res = wgt * res + (1.f - wgt) * locv[et];
            if (ISBF) ((u16*)outv)[oo + et * 16] = f2bf(res);
            else      ((float*)outv)[oo + et * 16] = res;
        }
    }
}

template <int PRE>
__global__ __launch_bounds__(512, 4) void attn_kernel(
    const void* __restrict__ qv, const void* __restrict__ kv,
    const void* __restrict__ vv, const void* __restrict__ alphav,
    void* __restrict__ outv, const u16* __restrict__ kb,
    const u16* __restrict__ vs)
{
    __shared__ u16 Vbuf[2 * 4096];      // double-buffered V tile image
    __shared__ u16 Plds[8 * 1024];      // per-wave P [query][key], swizzled

    const int isbf = detect_isbf16((const u32*)qv, threadIdx.x & 63);
    if (isbf) attn_impl<1, PRE>(qv, kv, vv, alphav, outv, kb, vs, Vbuf, Plds);
    else      attn_impl<0, PRE>(qv, kv, vv, alphav, outv, kb, vs, Vbuf, Plds);
}

extern "C" void kernel_launch(void* const* d_in, const int* in_sizes, int n_in,
                              void* d_out, int out_size, void* d_ws, size_t ws_size,
                              hipStream_t stream) {
    const void* q = d_in[0];
    const void* k = d_in[1];
    const void* v = d_in[2];
    const void* a = d_in[3];

    u16* kb = (u16*)d_ws;
    u16* vs = kb + 4194304;             // 8 MB offset (u16 elements)
    const bool usepre = (ws_size >= 16777216u);

    if (usepre) {
        hipLaunchKernelGGL(prep_kernel, dim3(2048), dim3(256), 0, stream,
                           q, k, v, kb, vs);
        hipLaunchKernelGGL(attn_kernel<1>, dim3(512), dim3(512), 0, stream,
                           q, k, v, a, d_out, kb, vs);
    } else {
        hipLaunchKernelGGL(attn_kernel<0>, dim3(512), dim3(512), 0, stream,
                           q, k, v, a, d_out, kb, vs);
    }
}